// Round 17
// baseline (236.406 us; speedup 1.0000x reference)
//
#include <hip/hip_runtime.h>

#define MDIM 32768
#define NDIM 4096
#define KDIM 1024

typedef __attribute__((ext_vector_type(4))) float floatx4;
typedef __attribute__((ext_vector_type(16))) float float16v;
typedef __attribute__((ext_vector_type(4))) int int4v;
typedef __attribute__((ext_vector_type(8))) int int8v;

// ---- quantize x: f32 [M,K] -> fp8 e4m3 bytes [M,K] (RNE, saturating) ----
__global__ __launch_bounds__(256) void quant_x_kernel(
    const float* __restrict__ x, char* __restrict__ out, int n16) {
    int idx = blockIdx.x * blockDim.x + threadIdx.x;
    int stride = gridDim.x * blockDim.x;
    const floatx4* xv = (const floatx4*)x;
    int4v* ov = (int4v*)out;
    for (int i = idx; i < n16; i += stride) {
        int4v o;
#pragma unroll
        for (int j = 0; j < 4; ++j) {
            floatx4 v = __builtin_nontemporal_load(&xv[i * 4 + j]);  // x never reused
            int pk = __builtin_amdgcn_cvt_pk_fp8_f32(v.x, v.y, 0, false);
            o[j] = __builtin_amdgcn_cvt_pk_fp8_f32(v.z, v.w, pk, true);
        }
        ov[i] = o;
    }
}

// ---- quantize + transpose w: f32 [K,N] -> fp8 e4m3 [N,K] row-major ----
__global__ __launch_bounds__(256) void quant_w_kernel(
    const float* __restrict__ w, char* __restrict__ wT) {
    __shared__ char tile[64][68];
    int nbase = blockIdx.x * 64;
    int kbase = blockIdx.y * 64;
    int t = threadIdx.x;
#pragma unroll
    for (int i = 0; i < 4; ++i) {
        int fidx = t + i * 256;
        int r = fidx >> 4;
        int c4 = fidx & 15;
        floatx4 v = *(const floatx4*)&w[(long)(kbase + r) * NDIM + nbase + c4 * 4];
        int pk = __builtin_amdgcn_cvt_pk_fp8_f32(v.x, v.y, 0, false);
        pk = __builtin_amdgcn_cvt_pk_fp8_f32(v.z, v.w, pk, true);
        *(int*)&tile[r][c4 * 4] = pk;
    }
    __syncthreads();
    int n = t >> 2, kq = (t & 3) * 16;
    int outw[4];
#pragma unroll
    for (int g = 0; g < 4; ++g) {
        int v = 0;
#pragma unroll
        for (int j = 0; j < 4; ++j)
            v |= ((int)(unsigned char)tile[kq + g * 4 + j][n]) << (8 * j);
        outw[g] = v;
    }
    *(int4v*)&wT[(long)(nbase + n) * KDIM + kbase + kq] = *(int4v*)outw;
}

// ======== GEMM: MX-fp8 (unit scales). A fp8 [M,K], BT fp8 [N,K], C f32 [M,N].
// r13 geometry (256x256 tile, BK=128, 8 K-tiles, 2 bufs A+B 128 KB, XOR
// swizzle chunk^=row&7, bm-major XCD order, NT C-stores) with ONE change:
// 16 WAVES per block (1024 thr, 4M x 4N wave grid, 64x64/wave, acc 2x2x16
// = 64 VGPR) -> 4 waves/SIMD instead of 2. Theory: the invariant ~7250
// cy/tile (vs ~3000 LDS + 2200 MFMA floors) across ALL r3-r16 schedule
// variants is latency-bound ds_read->MFMA chains with only 2 waves/SIMD to
// hide them; doubling resident waves at fixed tile/staging/geometry attacks
// exactly that term. Staging: 1024 thr x 16 B = 16 KB/GL -> 4 GLs/tile.

#define GL(gp, lp)                                                 \
    __builtin_amdgcn_global_load_lds(                              \
        (const __attribute__((address_space(1))) void*)(gp),       \
        (__attribute__((address_space(3))) void*)(lp), 16, 0, 0)

#define VMCNT(n) asm volatile("s_waitcnt vmcnt(" #n ")" ::: "memory")
#define BAR()    __builtin_amdgcn_s_barrier()
#define SP1 __builtin_amdgcn_s_setprio(1)
#define SP0 __builtin_amdgcn_s_setprio(0)

#define MFMA_SC(a_, b_, c_)                                               \
    __builtin_amdgcn_mfma_scale_f32_32x32x64_f8f6f4(                      \
        (a_), (b_), (c_), 0, 0, 0, 0x7F7F7F7F, 0, 0x7F7F7F7F)

__global__ __launch_bounds__(1024) void gemm_kernel(
    const char* __restrict__ A, const char* __restrict__ BT,
    const float* __restrict__ bias, float* __restrict__ C) {
    __shared__ char lds[131072];   // buf d: A at d*32768, B at 65536 + d*32768

    const int T = threadIdx.x;
    const int lane = T & 63;
    const int w = T >> 6;            // wave 0..15
    const int wr = w >> 2;           // 0..3 (M)
    const int wc = w & 3;            // 0..3 (N)

    // XCD-aware bijective swizzle (2048 blocks % 8 == 0), bm-MAJOR.
    const int sw = (blockIdx.x & 7) * 256 + (blockIdx.x >> 3);
    const int bm = (sw >> 4) * 256;
    const int bn = (sw & 15) * 256;

    // ---- staging: LDS phys chunk (T&7) of slab-row (T>>3) holds logical
    // chunk (T&7)^((T>>3)&7) (both-sides XOR involution; zero conflicts).
    // 1024 thr x 16 B = 16 KB = 128 rows per GL; 2 GLs cover 256 rows.
    const int cs = (T & 7) ^ ((T >> 3) & 7);
    const long aOff = (long)(bm + (T >> 3)) * KDIM + cs * 16;
    const long bOff = (long)(bn + (T >> 3)) * KDIM + cs * 16;
    const int dstB = (T >> 3) * 128 + (T & 7) * 16;

#define STG_A(d_, t_) { char* la_ = lds + (d_) * 32768 + dstB;                \
        const char* ga_ = A + aOff + (t_) * 128;                              \
        GL(ga_, la_); GL(ga_ + 128 * KDIM, la_ + 16384); }
#define STG_B(d_, t_) { char* lb_ = lds + 65536 + (d_) * 32768 + dstB;        \
        const char* gb_ = BT + bOff + (t_) * 128;                             \
        GL(gb_, lb_); GL(gb_ + 128 * KDIM, lb_ + 16384); }

    // ---- read-side addresses ----
    const int l31 = lane & 31;
    const int kh = lane >> 5;
    const int swz = (l31 & 7) << 4;
    const char* Abase = lds + (wr * 64 + l31) * 128;
    const char* Bbase = lds + 65536 + (wc * 64 + l31) * 128;

    float16v acc[2][2] = {};

#define LD32(dst_, base_, col0_) {                                        \
        int4v lo_ = *(const int4v*)((base_) + (((col0_) + 0) ^ swz));     \
        int4v hi_ = *(const int4v*)((base_) + (((col0_) + 16) ^ swz));    \
        dst_[0] = lo_[0]; dst_[1] = lo_[1]; dst_[2] = lo_[2]; dst_[3] = lo_[3]; \
        dst_[4] = hi_[0]; dst_[5] = hi_[1]; dst_[6] = hi_[2]; dst_[7] = hi_[3]; \
    }

    // Tile body: 2 phases (one per kk-half), each { 4 LD32 -> 1 staging GL
    // pair -> barrier -> setprio(1) + 4 MFMA + setprio(0) -> barrier }.
#define TILE(c_, s0_, s1_, vm_) {                                         \
        const char* ap_ = Abase + (c_) * 32768;                           \
        const char* bp_ = Bbase + (c_) * 32768;                           \
        int8v a0, a1, b0, b1;                                             \
        /* P0: kk0 */                                                     \
        LD32(b0, bp_, kh * 32);        LD32(b1, bp_ + 4096, kh * 32);     \
        LD32(a0, ap_, kh * 32);        LD32(a1, ap_ + 4096, kh * 32);     \
        s0_;                                                              \
        BAR();                                                            \
        SP1;                                                              \
        acc[0][0] = MFMA_SC(a0, b0, acc[0][0]);                           \
        acc[0][1] = MFMA_SC(a0, b1, acc[0][1]);                           \
        acc[1][0] = MFMA_SC(a1, b0, acc[1][0]);                           \
        acc[1][1] = MFMA_SC(a1, b1, acc[1][1]);                           \
        SP0;                                                              \
        BAR();                                                            \
        /* P1: kk1 */                                                     \
        LD32(b0, bp_, 64 + kh * 32);     LD32(b1, bp_ + 4096, 64 + kh * 32); \
        LD32(a0, ap_, 64 + kh * 32);     LD32(a1, ap_ + 4096, 64 + kh * 32); \
        s1_;                                                              \
        BAR();                                                            \
        SP1;                                                              \
        acc[0][0] = MFMA_SC(a0, b0, acc[0][0]);                           \
        acc[0][1] = MFMA_SC(a0, b1, acc[0][1]);                           \
        acc[1][0] = MFMA_SC(a1, b0, acc[1][0]);                           \
        acc[1][1] = MFMA_SC(a1, b1, acc[1][1]);                           \
        SP0;                                                              \
        vm_;                                                              \
        BAR();                                                            \
    }

    // ---- prologue: stage tile 0 into buf 0, gate ----
    STG_A(0, 0); STG_B(0, 0);
    VMCNT(0); BAR();

    // ---- 8 K-tiles; tile t stages t+1 into buf c^1, 1 GL-pair per phase ----
    TILE(0, STG_A(1, 1), STG_B(1, 1), VMCNT(0));
    TILE(1, STG_A(0, 2), STG_B(0, 2), VMCNT(0));
    TILE(0, STG_A(1, 3), STG_B(1, 3), VMCNT(0));
    TILE(1, STG_A(0, 4), STG_B(0, 4), VMCNT(0));
    TILE(0, STG_A(1, 5), STG_B(1, 5), VMCNT(0));
    TILE(1, STG_A(0, 6), STG_B(0, 6), VMCNT(0));
    TILE(0, STG_A(1, 7), STG_B(1, 7), VMCNT(0));
    TILE(1, (void)0, (void)0, (void)0);

    // ---- C write + bias (non-temporal). 32x32 C/D frag:
    // col=lane&31, row=(r&3)+8*(r>>2)+4*kh.
#pragma unroll
    for (int n = 0; n < 2; ++n) {
        int gcol = bn + wc * 64 + n * 32 + l31;
        float bv = bias[gcol];
#pragma unroll
        for (int m = 0; m < 2; ++m) {
            long rbase = bm + wr * 64 + m * 32 + 4 * kh;
#pragma unroll
            for (int r = 0; r < 16; ++r) {
                long grow = rbase + (r & 3) + 8 * (r >> 2);
                __builtin_nontemporal_store(acc[m][n][r] + bv, &C[grow * NDIM + gcol]);
            }
        }
    }
#undef STG_A
#undef STG_B
#undef TILE
#undef LD32
}

extern "C" void kernel_launch(void* const* d_in, const int* in_sizes, int n_in,
                              void* d_out, int out_size, void* d_ws, size_t ws_size,
                              hipStream_t stream) {
    (void)in_sizes; (void)n_in; (void)out_size; (void)ws_size;
    const float* x = (const float*)d_in[0];
    const float* wk = (const float*)d_in[1];
    const float* bias = (const float*)d_in[2];
    float* out = (float*)d_out;

    char* xq = (char*)d_ws;                                       // 32 MB
    char* wT = (char*)d_ws + (size_t)MDIM * KDIM;                 // 4 MB

    quant_x_kernel<<<2048, 256, 0, stream>>>(x, xq, MDIM * KDIM / 16);
    quant_w_kernel<<<dim3(NDIM / 64, KDIM / 64), 256, 0, stream>>>(wk, wT);
    gemm_kernel<<<2048, 1024, 0, stream>>>(xq, wT, bias, out);
}

// Round 18
// 225.674 us; speedup vs baseline: 1.0476x; 1.0476x over previous
//
#include <hip/hip_runtime.h>

#define MDIM 32768
#define NDIM 4096
#define KDIM 1024

typedef __attribute__((ext_vector_type(4))) float floatx4;
typedef __attribute__((ext_vector_type(16))) float float16v;
typedef __attribute__((ext_vector_type(4))) int int4v;
typedef __attribute__((ext_vector_type(8))) int int8v;

// ---- quantize x: f32 [M,K] -> fp8 e4m3 bytes [M,K] (RNE, saturating) ----
__global__ __launch_bounds__(256) void quant_x_kernel(
    const float* __restrict__ x, char* __restrict__ out, int n16) {
    int idx = blockIdx.x * blockDim.x + threadIdx.x;
    int stride = gridDim.x * blockDim.x;
    const floatx4* xv = (const floatx4*)x;
    int4v* ov = (int4v*)out;
    for (int i = idx; i < n16; i += stride) {
        int4v o;
#pragma unroll
        for (int j = 0; j < 4; ++j) {
            floatx4 v = __builtin_nontemporal_load(&xv[i * 4 + j]);  // x never reused
            int pk = __builtin_amdgcn_cvt_pk_fp8_f32(v.x, v.y, 0, false);
            o[j] = __builtin_amdgcn_cvt_pk_fp8_f32(v.z, v.w, pk, true);
        }
        ov[i] = o;
    }
}

// ---- quantize + transpose w: f32 [K,N] -> fp8 e4m3 [N,K] row-major ----
__global__ __launch_bounds__(256) void quant_w_kernel(
    const float* __restrict__ w, char* __restrict__ wT) {
    __shared__ char tile[64][68];
    int nbase = blockIdx.x * 64;
    int kbase = blockIdx.y * 64;
    int t = threadIdx.x;
#pragma unroll
    for (int i = 0; i < 4; ++i) {
        int fidx = t + i * 256;
        int r = fidx >> 4;
        int c4 = fidx & 15;
        floatx4 v = *(const floatx4*)&w[(long)(kbase + r) * NDIM + nbase + c4 * 4];
        int pk = __builtin_amdgcn_cvt_pk_fp8_f32(v.x, v.y, 0, false);
        pk = __builtin_amdgcn_cvt_pk_fp8_f32(v.z, v.w, pk, true);
        *(int*)&tile[r][c4 * 4] = pk;
    }
    __syncthreads();
    int n = t >> 2, kq = (t & 3) * 16;
    int outw[4];
#pragma unroll
    for (int g = 0; g < 4; ++g) {
        int v = 0;
#pragma unroll
        for (int j = 0; j < 4; ++j)
            v |= ((int)(unsigned char)tile[kq + g * 4 + j][n]) << (8 * j);
        outw[g] = v;
    }
    *(int4v*)&wT[(long)(nbase + n) * KDIM + kbase + kq] = *(int4v*)outw;
}

// ======== GEMM: MX-fp8 (unit scales). A fp8 [M,K], BT fp8 [N,K], C f32 [M,N].
// FINAL (r13/r16, 225.8-225.9 us, reproduced twice): 256x256 tile, BK=128,
// 8 K-tiles, 2 bufs, 8 waves 2Mx4N, 4-phase interleave per tile
//   { ds_read subtile -> 2 staging GLs (next tile) -> s_barrier ->
//     setprio(1) + 4 MFMA + setprio(0) -> s_barrier }
// XOR swizzle chunk^=row&7 (zero bank conflicts, verified r1-r17), bm-major
// XCD swizzle (best of 4 orderings), NT C-stores. Full session ledger:
// phase shape (r4/r5/r13) / barrier count (r8) / LDS traffic (r8) /
// blocks-per-CU (r9/r10) / waves-per-SIMD (r17) / B-direct (r7/r8) /
// zero-LDS (r12) / in-kernel fusion (r11) / 4 block orderings — all
// flat-to-worse. Structure is at its practical plateau: ~1 GB LDS staging
// (128-VGPR acc caps tile reuse at 256^2), 512 MB serial per-block C-drain,
// GEMM ~1.25x its optimistic HBM+staging floor. absmax 0.015625 (5x margin).

#define GL(gp, lp)                                                 \
    __builtin_amdgcn_global_load_lds(                              \
        (const __attribute__((address_space(1))) void*)(gp),       \
        (__attribute__((address_space(3))) void*)(lp), 16, 0, 0)

#define VMCNT(n) asm volatile("s_waitcnt vmcnt(" #n ")" ::: "memory")
#define BAR()    __builtin_amdgcn_s_barrier()
#define SP1 __builtin_amdgcn_s_setprio(1)
#define SP0 __builtin_amdgcn_s_setprio(0)

#define MFMA_SC(a_, b_, c_)                                               \
    __builtin_amdgcn_mfma_scale_f32_32x32x64_f8f6f4(                      \
        (a_), (b_), (c_), 0, 0, 0, 0x7F7F7F7F, 0, 0x7F7F7F7F)

__global__ __launch_bounds__(512) void gemm_kernel(
    const char* __restrict__ A, const char* __restrict__ BT,
    const float* __restrict__ bias, float* __restrict__ C) {
    __shared__ char lds[131072];   // buf d: A at d*32768, B at 65536 + d*32768

    const int T = threadIdx.x;
    const int lane = T & 63;
    const int w = T >> 6;            // wave 0..7
    const int wr = w >> 2;           // 0..1 (M)
    const int wc = w & 3;            // 0..3 (N)

    // XCD-aware bijective swizzle (2048 blocks % 8 == 0), bm-MAJOR.
    const int sw = (blockIdx.x & 7) * 256 + (blockIdx.x >> 3);
    const int bm = (sw >> 4) * 256;
    const int bn = (sw & 15) * 256;

    // ---- staging: LDS phys chunk (T&7) of slab-row (T>>3) holds logical
    // chunk (T&7)^((T>>3)&7) (both-sides XOR involution; zero conflicts).
    const int cs = (T & 7) ^ ((T >> 3) & 7);
    const long aOff = (long)(bm + (T >> 3)) * KDIM + cs * 16;
    const long bOff = (long)(bn + (T >> 3)) * KDIM + cs * 16;
    const int dstB = (T >> 3) * 128 + (T & 7) * 16;

    // staging split into 4 GL-pairs (fine interleave)
#define STG_A0(d_, t_) { char* la_ = lds + (d_) * 32768 + dstB;               \
        const char* ga_ = A + aOff + (t_) * 128;                              \
        GL(ga_, la_); GL(ga_ + 64 * KDIM, la_ + 8192); }
#define STG_A1(d_, t_) { char* la_ = lds + (d_) * 32768 + dstB;               \
        const char* ga_ = A + aOff + (t_) * 128;                              \
        GL(ga_ + 128 * KDIM, la_ + 16384); GL(ga_ + 192 * KDIM, la_ + 24576); }
#define STG_B0(d_, t_) { char* lb_ = lds + 65536 + (d_) * 32768 + dstB;       \
        const char* gb_ = BT + bOff + (t_) * 128;                             \
        GL(gb_, lb_); GL(gb_ + 64 * KDIM, lb_ + 8192); }
#define STG_B1(d_, t_) { char* lb_ = lds + 65536 + (d_) * 32768 + dstB;       \
        const char* gb_ = BT + bOff + (t_) * 128;                             \
        GL(gb_ + 128 * KDIM, lb_ + 16384); GL(gb_ + 192 * KDIM, lb_ + 24576); }

    // ---- read-side addresses ----
    const int l31 = lane & 31;
    const int kh = lane >> 5;
    const int swz = (l31 & 7) << 4;
    const char* Abase = lds + (wr * 128 + l31) * 128;
    const char* Bbase = lds + 65536 + (wc * 64 + l31) * 128;

    float16v acc[4][2] = {};

#define LD32(dst_, base_, col0_) {                                        \
        int4v lo_ = *(const int4v*)((base_) + (((col0_) + 0) ^ swz));     \
        int4v hi_ = *(const int4v*)((base_) + (((col0_) + 16) ^ swz));    \
        dst_[0] = lo_[0]; dst_[1] = lo_[1]; dst_[2] = lo_[2]; dst_[3] = lo_[3]; \
        dst_[4] = hi_[0]; dst_[5] = hi_[1]; dst_[6] = hi_[2]; dst_[7] = hi_[3]; \
    }

    // Tile body: 4 phases. s0..s3 = staging statements (2 GLs each) for the
    // next tile; vm_ = end-of-tile vmcnt gate (VMCNT(0) or nothing).
#define TILE(c_, s0_, s1_, s2_, s3_, vm_) {                               \
        const char* ap_ = Abase + (c_) * 32768;                           \
        const char* bp_ = Bbase + (c_) * 32768;                           \
        int8v a0, a1, a2, a3, b0, b1;                                     \
        /* P0: kk0, m-pair 0 */                                           \
        LD32(b0, bp_, kh * 32);        LD32(b1, bp_ + 4096, kh * 32);     \
        LD32(a0, ap_, kh * 32);        LD32(a1, ap_ + 4096, kh * 32);     \
        s0_;                                                              \
        BAR();                                                            \
        SP1;                                                              \
        acc[0][0] = MFMA_SC(a0, b0, acc[0][0]);                           \
        acc[0][1] = MFMA_SC(a0, b1, acc[0][1]);                           \
        acc[1][0] = MFMA_SC(a1, b0, acc[1][0]);                           \
        acc[1][1] = MFMA_SC(a1, b1, acc[1][1]);                           \
        SP0;                                                              \
        BAR();                                                            \
        /* P1: kk0, m-pair 1 */                                           \
        LD32(a2, ap_ + 8192, kh * 32); LD32(a3, ap_ + 12288, kh * 32);    \
        s1_;                                                              \
        BAR();                                                            \
        SP1;                                                              \
        acc[2][0] = MFMA_SC(a2, b0, acc[2][0]);                           \
        acc[2][1] = MFMA_SC(a2, b1, acc[2][1]);                           \
        acc[3][0] = MFMA_SC(a3, b0, acc[3][0]);                           \
        acc[3][1] = MFMA_SC(a3, b1, acc[3][1]);                           \
        SP0;                                                              \
        BAR();                                                            \
        /* P2: kk1, m-pair 0 */                                           \
        LD32(b0, bp_, 64 + kh * 32);     LD32(b1, bp_ + 4096, 64 + kh * 32); \
        LD32(a0, ap_, 64 + kh * 32);     LD32(a1, ap_ + 4096, 64 + kh * 32); \
        s2_;                                                              \
        BAR();                                                            \
        SP1;                                                              \
        acc[0][0] = MFMA_SC(a0, b0, acc[0][0]);                           \
        acc[0][1] = MFMA_SC(a0, b1, acc[0][1]);                           \
        acc[1][0] = MFMA_SC(a1, b0, acc[1][0]);                           \
        acc[1][1] = MFMA_SC(a1, b1, acc[1][1]);                           \
        SP0;                                                              \
        BAR();                                                            \
        /* P3: kk1, m-pair 1 */                                           \
        LD32(a2, ap_ + 8192, 64 + kh * 32); LD32(a3, ap_ + 12288, 64 + kh * 32); \
        s3_;                                                              \
        BAR();                                                            \
        SP1;                                                              \
        acc[2][0] = MFMA_SC(a2, b0, acc[2][0]);                           \
        acc[2][1] = MFMA_SC(a2, b1, acc[2][1]);                           \
        acc[3][0] = MFMA_SC(a3, b0, acc[3][0]);                           \
        acc[3][1] = MFMA_SC(a3, b1, acc[3][1]);                           \
        SP0;                                                              \
        vm_;                                                              \
        BAR();                                                            \
    }

    // ---- prologue: stage tile 0 into buf 0, gate ----
    STG_A0(0, 0); STG_A1(0, 0); STG_B0(0, 0); STG_B1(0, 0);
    VMCNT(0); BAR();

    // ---- 8 K-tiles; tile t stages t+1 into buf c^1, 2 GLs per phase ----
    TILE(0, STG_A0(1, 1), STG_A1(1, 1), STG_B0(1, 1), STG_B1(1, 1), VMCNT(0));
    TILE(1, STG_A0(0, 2), STG_A1(0, 2), STG_B0(0, 2), STG_B1(0, 2), VMCNT(0));
    TILE(0, STG_A0(1, 3), STG_A1(1, 3), STG_B0(1, 3), STG_B1(1, 3), VMCNT(0));
    TILE(1, STG_A0(0, 4), STG_A1(0, 4), STG_B0(0, 4), STG_B1(0, 4), VMCNT(0));
    TILE(0, STG_A0(1, 5), STG_A1(1, 5), STG_B0(1, 5), STG_B1(1, 5), VMCNT(0));
    TILE(1, STG_A0(0, 6), STG_A1(0, 6), STG_B0(0, 6), STG_B1(0, 6), VMCNT(0));
    TILE(0, STG_A0(1, 7), STG_A1(1, 7), STG_B0(1, 7), STG_B1(1, 7), VMCNT(0));
    TILE(1, (void)0, (void)0, (void)0, (void)0, (void)0);

    // ---- C write + bias (non-temporal). 32x32 C/D frag:
    // col=lane&31, row=(r&3)+8*(r>>2)+4*kh.
#pragma unroll
    for (int n = 0; n < 2; ++n) {
        int gcol = bn + wc * 64 + n * 32 + l31;
        float bv = bias[gcol];
#pragma unroll
        for (int m = 0; m < 4; ++m) {
            long rbase = bm + wr * 128 + m * 32 + 4 * kh;
#pragma unroll
            for (int r = 0; r < 16; ++r) {
                long grow = rbase + (r & 3) + 8 * (r >> 2);
                __builtin_nontemporal_store(acc[m][n][r] + bv, &C[grow * NDIM + gcol]);
            }
        }
    }
#undef STG_A0
#undef STG_A1
#undef STG_B0
#undef STG_B1
#undef TILE
#undef LD32
}

extern "C" void kernel_launch(void* const* d_in, const int* in_sizes, int n_in,
                              void* d_out, int out_size, void* d_ws, size_t ws_size,
                              hipStream_t stream) {
    (void)in_sizes; (void)n_in; (void)out_size; (void)ws_size;
    const float* x = (const float*)d_in[0];
    const float* wk = (const float*)d_in[1];
    const float* bias = (const float*)d_in[2];
    float* out = (float*)d_out;

    char* xq = (char*)d_ws;                                       // 32 MB
    char* wT = (char*)d_ws + (size_t)MDIM * KDIM;                 // 4 MB

    quant_x_kernel<<<2048, 256, 0, stream>>>(x, xq, MDIM * KDIM / 16);
    quant_w_kernel<<<dim3(NDIM / 64, KDIM / 64), 256, 0, stream>>>(wk, wT);
    gemm_kernel<<<2048, 512, 0, stream>>>(xq, wT, bias, out);
}